// Round 2
// baseline (537.194 us; speedup 1.0000x reference)
//
#include <hip/hip_runtime.h>
#include <math.h>

// Problem constants (from reference: MB=8, SEQ=2048, EMBDIM=64, N_TOKENS=8192)
#define EMB     64
#define NTOK    8192
#define NQ      16384             // MB*SEQ queries
#define TPB     256
#define MAXSPLIT 16

// ---------------------------------------------------------------------------
// Kernel 1: ||w_c||^2 for every codeword -> ws table
// ---------------------------------------------------------------------------
__global__ void ynorm_kernel(const float* __restrict__ W, float* __restrict__ ynorm) {
    int c = blockIdx.x * blockDim.x + threadIdx.x;
    if (c >= NTOK) return;
    const float4* w4 = (const float4*)(W + (size_t)c * EMB);
    float s = 0.f;
#pragma unroll
    for (int i = 0; i < EMB / 4; ++i) {
        float4 v = w4[i];
        s = fmaf(v.x, v.x, s);
        s = fmaf(v.y, v.y, s);
        s = fmaf(v.z, v.z, s);
        s = fmaf(v.w, v.w, s);
    }
    ynorm[c] = s;
}

// ---------------------------------------------------------------------------
// Kernel 2: register-resident-x / SGPR-w distance + per-lane argmin.
// One query per lane (x[64] in VGPRs). Codeword index c is wave-uniform, so
// W[c*64+d] scalarizes to s_load (SMEM pipe) and v_fma_f32 reads the SGPR
// directly — ZERO LDS and near-zero VMEM in the hot loop. 4 independent
// accumulator chains give the FMA pipe enough ILP to issue back-to-back.
// Argmin is per-lane: no cross-lane reduction, no barriers.
// ---------------------------------------------------------------------------
__global__ __launch_bounds__(TPB, 4) void vq_argmin_kernel(
    const float* __restrict__ X, const float* __restrict__ W,
    const float* __restrict__ ynorm,
    float* __restrict__ pval, int* __restrict__ pidx, int cpw)
{
    const int q     = blockIdx.x * TPB + threadIdx.x;  // one query per thread
    const int split = blockIdx.y;
    const int c0    = split * cpw;

    // --- load this lane's query vector into registers (one-time, L2-served) ---
    float x[EMB];
    {
        const float4* xp = (const float4*)(X + (size_t)q * EMB);
#pragma unroll
        for (int i = 0; i < EMB / 4; ++i) {
            float4 v = xp[i];
            x[4 * i + 0] = v.x;
            x[4 * i + 1] = v.y;
            x[4 * i + 2] = v.z;
            x[4 * i + 3] = v.w;
        }
    }

    float minv = INFINITY;
    int   mini = 0;

#pragma unroll 2
    for (int c = c0; c < c0 + cpw; ++c) {
        const float* __restrict__ w = W + (size_t)c * EMB;   // wave-uniform -> s_load
        float a0 = 0.f, a1 = 0.f, a2 = 0.f, a3 = 0.f;
#pragma unroll
        for (int d = 0; d < EMB; d += 4) {
            a0 = fmaf(x[d + 0], w[d + 0], a0);
            a1 = fmaf(x[d + 1], w[d + 1], a1);
            a2 = fmaf(x[d + 2], w[d + 2], a2);
            a3 = fmaf(x[d + 3], w[d + 3], a3);
        }
        float dot = (a0 + a1) + (a2 + a3);
        float s = fmaf(-2.0f, dot, ynorm[c]);   // ynorm[c] wave-uniform -> SGPR
        if (s < minv) { minv = s; mini = c; }   // increasing c + strict < = first-wins
    }

    pval[(size_t)split * NQ + q] = minv;
    pidx[(size_t)split * NQ + q] = mini;
}

// ---------------------------------------------------------------------------
// Kernel 3: combine split partials -> final int32 indices
// ---------------------------------------------------------------------------
__global__ void combine_kernel(const float* __restrict__ pval,
                               const int* __restrict__ pidx,
                               int* __restrict__ out, int nsplit)
{
    int q = blockIdx.x * blockDim.x + threadIdx.x;
    if (q >= NQ) return;
    float bv = pval[q];
    int   bi = pidx[q];
    for (int s = 1; s < nsplit; ++s) {
        float v  = pval[(size_t)s * NQ + q];
        int   i2 = pidx[(size_t)s * NQ + q];
        if (v < bv || (v == bv && i2 < bi)) { bv = v; bi = i2; }
    }
    out[q] = bi;
}

// ---------------------------------------------------------------------------
extern "C" void kernel_launch(void* const* d_in, const int* in_sizes, int n_in,
                              void* d_out, int out_size, void* d_ws, size_t ws_size,
                              hipStream_t stream) {
    const float* X = (const float*)d_in[0];   // [16384, 64]
    const float* W = (const float*)d_in[1];   // [8192, 64]

    // Workspace layout: ynorm | pval | pidx. Pick split count ws permits
    // (deterministic across calls since ws_size is constant).
    size_t avail = (ws_size > (size_t)NTOK * 4) ? (ws_size - (size_t)NTOK * 4) : 0;
    int nsplit = (int)(avail / ((size_t)NQ * 8));
    if (nsplit > MAXSPLIT) nsplit = MAXSPLIT;
    if (nsplit < 1) nsplit = 1;
    // round down to a divisor of 8192 (power of two)
    while (nsplit & (nsplit - 1)) nsplit &= nsplit - 1;
    int cpw = NTOK / nsplit;

    float* ynorm = (float*)d_ws;                         // 8192 f
    float* pval  = ynorm + NTOK;                         // nsplit*NQ f
    int*   pidx  = (int*)(pval + (size_t)nsplit * NQ);   // nsplit*NQ i
    int*   out   = (int*)d_out;                          // 16384 i32

    ynorm_kernel<<<NTOK / TPB, TPB, 0, stream>>>(W, ynorm);
    dim3 grid(NQ / TPB, nsplit);
    vq_argmin_kernel<<<grid, TPB, 0, stream>>>(X, W, ynorm, pval, pidx, cpw);
    combine_kernel<<<NQ / TPB, TPB, 0, stream>>>(pval, pidx, out, nsplit);
}

// Round 3
// 155.594 us; speedup vs baseline: 3.4525x; 3.4525x over previous
//
#include <hip/hip_runtime.h>
#include <math.h>

// Problem: X[16384,64] fp32, W[8192,64] fp32 -> argmin_c ||x-w_c||^2 (int32)
#define EMB     64
#define NTOK    8192
#define NQ      16384
#define TPB     256
#define CSPLIT  4
#define CRANGE  (NTOK / CSPLIT)   // 2048 codewords per block
#define BQ      128               // query rows per block
#define TILE_C  128               // codewords staged in LDS per iteration
#define ROWP    72                // padded LDS row (fp16 elems): 144 B -> even bank spread

typedef _Float16 half8 __attribute__((ext_vector_type(8)));
typedef float    f32x4 __attribute__((ext_vector_type(4)));

// ---------------------------------------------------------------------------
// Prep A: ||w_c||^2 in fp32 (exact-order-insensitive; matches ref to ~1e-5)
// ---------------------------------------------------------------------------
__global__ void ynorm_kernel(const float* __restrict__ W, float* __restrict__ ynorm) {
    int c = blockIdx.x * blockDim.x + threadIdx.x;
    if (c >= NTOK) return;
    const float4* w4 = (const float4*)(W + (size_t)c * EMB);
    float s = 0.f;
#pragma unroll
    for (int i = 0; i < EMB / 4; ++i) {
        float4 v = w4[i];
        s = fmaf(v.x, v.x, s); s = fmaf(v.y, v.y, s);
        s = fmaf(v.z, v.z, s); s = fmaf(v.w, v.w, s);
    }
    ynorm[c] = s;
}

// ---------------------------------------------------------------------------
// Prep B: split W into fp16 hi + fp16 lo (w ~= wh + wl, residual ~2^-22)
// ---------------------------------------------------------------------------
__global__ void wsplit_kernel(const float* __restrict__ W,
                              _Float16* __restrict__ Wh, _Float16* __restrict__ Wl) {
    int u = blockIdx.x * blockDim.x + threadIdx.x;   // 0 .. 8192*8-1
    int c = u >> 3, seg = u & 7;
    const float* wp = W + (size_t)c * EMB + seg * 8;
    float4 v0 = *(const float4*)wp;
    float4 v1 = *(const float4*)(wp + 4);
    float xv[8] = {v0.x, v0.y, v0.z, v0.w, v1.x, v1.y, v1.z, v1.w};
    half8 h, l;
#pragma unroll
    for (int j = 0; j < 8; ++j) {
        _Float16 hh = (_Float16)xv[j];
        h[j] = hh;
        l[j] = (_Float16)(xv[j] - (float)hh);
    }
    *(half8*)(Wh + (size_t)c * EMB + seg * 8) = h;
    *(half8*)(Wl + (size_t)c * EMB + seg * 8) = l;
}

// ---------------------------------------------------------------------------
// Main: fp16x4-split MFMA distance + argmin.
// Block: 4 waves = 2(q-half: 64 rows) x 2(c-half: 64 cols of the staged 128).
// A (X hi/lo) lives in registers; W tile (hi/lo) staged in LDS with +8 pad.
// MFMA 16x16x32_f16: A[m=lane&15][k=(lane>>4)*8+j]; C col=lane&15,
// row=(lane>>4)*4+reg (measured layouts, learn_hip m89/m91).
// acc is folded into running per-lane argmin after every 16-col tile, so only
// 4 f32x4 accumulators are live -> ~160 VGPRs total.
// ---------------------------------------------------------------------------
__global__ __launch_bounds__(TPB, 3) void vq_mfma_kernel(
    const float* __restrict__ X,
    const _Float16* __restrict__ Wh, const _Float16* __restrict__ Wl,
    const float* __restrict__ ynorm,
    float* __restrict__ pval, int* __restrict__ pidx)
{
    __shared__ _Float16 Lh[TILE_C][ROWP];
    __shared__ _Float16 Ll[TILE_C][ROWP];
    __shared__ float    Lyn[TILE_C];
    __shared__ float    RedV[2][BQ];
    __shared__ int      RedI[2][BQ];

    const int t    = threadIdx.x;
    const int lane = t & 63;
    const int wid  = t >> 6;       // 0..3
    const int wq   = wid & 1;      // q half (0/1)
    const int wy   = wid >> 1;     // c half (0/1)
    const int l15  = lane & 15;
    const int lq   = lane >> 4;    // 0..3

    const int qblk   = blockIdx.x * BQ;
    const int qbase  = qblk + wq * 64;
    const int cbase0 = blockIdx.y * CRANGE;

    // --- A fragments: X rows (qbase + mt*16 + l15), k = kb*32 + lq*8 + j ---
    half8 ah[4][2], al[4][2];
#pragma unroll
    for (int mt = 0; mt < 4; ++mt) {
#pragma unroll
        for (int kb = 0; kb < 2; ++kb) {
            const float* xp = X + (size_t)(qbase + mt * 16 + l15) * EMB + kb * 32 + lq * 8;
            float4 v0 = *(const float4*)xp;
            float4 v1 = *(const float4*)(xp + 4);
            float xv[8] = {v0.x, v0.y, v0.z, v0.w, v1.x, v1.y, v1.z, v1.w};
            half8 h, l;
#pragma unroll
            for (int j = 0; j < 8; ++j) {
                _Float16 hh = (_Float16)xv[j];
                h[j] = hh;
                l[j] = (_Float16)(xv[j] - (float)hh);
            }
            ah[mt][kb] = h;
            al[mt][kb] = l;
        }
    }

    float minv[4][4];
    int   mini[4][4];
#pragma unroll
    for (int mt = 0; mt < 4; ++mt)
#pragma unroll
        for (int r = 0; r < 4; ++r) { minv[mt][r] = INFINITY; mini[mt][r] = 0; }

    const f32x4 zero4 = {0.f, 0.f, 0.f, 0.f};

    for (int c0 = 0; c0 < CRANGE; c0 += TILE_C) {
        const int cb = cbase0 + c0;

        __syncthreads();   // previous-iter LDS reads done before overwrite
        // --- stage W tile (hi/lo) + ynorm tile into LDS ---
        for (int u = t; u < TILE_C * 8; u += TPB) {
            int row = u >> 3, seg = u & 7;
            *(half8*)&Lh[row][seg * 8] = *(const half8*)(Wh + (size_t)(cb + row) * EMB + seg * 8);
            *(half8*)&Ll[row][seg * 8] = *(const half8*)(Wl + (size_t)(cb + row) * EMB + seg * 8);
        }
        if (t < TILE_C / 4) *(float4*)&Lyn[t * 4] = *(const float4*)(ynorm + cb + t * 4);
        __syncthreads();

#pragma unroll
        for (int ct = 0; ct < 4; ++ct) {
            const int ccol = wy * 64 + ct * 16;   // tile-local col base for this wave
            f32x4 acc[4];
            {
                // kb = 0 (k = 0..31)
                half8 bh = *(const half8*)&Lh[ccol + l15][lq * 8];
                half8 bl = *(const half8*)&Ll[ccol + l15][lq * 8];
#pragma unroll
                for (int mt = 0; mt < 4; ++mt) {
                    f32x4 a = __builtin_amdgcn_mfma_f32_16x16x32_f16(al[mt][0], bl, zero4, 0, 0, 0);
                    a = __builtin_amdgcn_mfma_f32_16x16x32_f16(al[mt][0], bh, a, 0, 0, 0);
                    a = __builtin_amdgcn_mfma_f32_16x16x32_f16(ah[mt][0], bl, a, 0, 0, 0);
                    a = __builtin_amdgcn_mfma_f32_16x16x32_f16(ah[mt][0], bh, a, 0, 0, 0);
                    acc[mt] = a;
                }
                // kb = 1 (k = 32..63)
                bh = *(const half8*)&Lh[ccol + l15][32 + lq * 8];
                bl = *(const half8*)&Ll[ccol + l15][32 + lq * 8];
#pragma unroll
                for (int mt = 0; mt < 4; ++mt) {
                    f32x4 a = acc[mt];
                    a = __builtin_amdgcn_mfma_f32_16x16x32_f16(al[mt][1], bl, a, 0, 0, 0);
                    a = __builtin_amdgcn_mfma_f32_16x16x32_f16(al[mt][1], bh, a, 0, 0, 0);
                    a = __builtin_amdgcn_mfma_f32_16x16x32_f16(ah[mt][1], bl, a, 0, 0, 0);
                    a = __builtin_amdgcn_mfma_f32_16x16x32_f16(ah[mt][1], bh, a, 0, 0, 0);
                    acc[mt] = a;
                }
            }
            // --- epilogue: dist = ynorm - 2*dot; running argmin (c ascending, strict <) ---
            const float yn   = Lyn[ccol + l15];
            const int   cidx = cb + ccol + l15;
#pragma unroll
            for (int mt = 0; mt < 4; ++mt) {
#pragma unroll
                for (int r = 0; r < 4; ++r) {
                    float s = fmaf(-2.f, acc[mt][r], yn);
                    if (s < minv[mt][r]) { minv[mt][r] = s; mini[mt][r] = cidx; }
                }
            }
        }
    }

    // --- cross-lane: reduce over the 16 col-lanes (xor on low 4 lane bits) ---
#pragma unroll
    for (int mt = 0; mt < 4; ++mt) {
#pragma unroll
        for (int r = 0; r < 4; ++r) {
            float v = minv[mt][r];
            int   i = mini[mt][r];
#pragma unroll
            for (int m = 1; m <= 8; m <<= 1) {
                float ov = __shfl_xor(v, m, 64);
                int   oi = __shfl_xor(i, m, 64);
                if (ov < v || (ov == v && oi < i)) { v = ov; i = oi; }
            }
            if (l15 == 0) {
                int qoff = wq * 64 + mt * 16 + lq * 4 + r;   // row within block
                RedV[wy][qoff] = v;
                RedI[wy][qoff] = i;
            }
        }
    }
    __syncthreads();

    // --- combine the two c-halves, write per-split partial ---
    if (t < BQ) {
        float v0 = RedV[0][t]; int i0 = RedI[0][t];
        float v1 = RedV[1][t]; int i1 = RedI[1][t];
        if (v1 < v0 || (v1 == v0 && i1 < i0)) { v0 = v1; i0 = i1; }
        size_t o = (size_t)blockIdx.y * NQ + qblk + t;
        pval[o] = v0;
        pidx[o] = i0;
    }
}

// ---------------------------------------------------------------------------
// Combine CSPLIT partials -> final int32 indices
// ---------------------------------------------------------------------------
__global__ void combine_kernel(const float* __restrict__ pval,
                               const int* __restrict__ pidx,
                               int* __restrict__ out)
{
    int q = blockIdx.x * blockDim.x + threadIdx.x;
    if (q >= NQ) return;
    float bv = pval[q];
    int   bi = pidx[q];
#pragma unroll
    for (int s = 1; s < CSPLIT; ++s) {
        float v  = pval[(size_t)s * NQ + q];
        int   i2 = pidx[(size_t)s * NQ + q];
        if (v < bv || (v == bv && i2 < bi)) { bv = v; bi = i2; }
    }
    out[q] = bi;
}

// ---------------------------------------------------------------------------
extern "C" void kernel_launch(void* const* d_in, const int* in_sizes, int n_in,
                              void* d_out, int out_size, void* d_ws, size_t ws_size,
                              hipStream_t stream) {
    const float* X = (const float*)d_in[0];   // [16384, 64]
    const float* W = (const float*)d_in[1];   // [8192, 64]

    // ws layout: Wh(1MB) | Wl(1MB) | ynorm(32KB) | pval(256KB) | pidx(256KB)
    _Float16* Wh    = (_Float16*)d_ws;
    _Float16* Wl    = Wh + (size_t)NTOK * EMB;
    float*    ynorm = (float*)(Wl + (size_t)NTOK * EMB);
    float*    pval  = ynorm + NTOK;
    int*      pidx  = (int*)(pval + (size_t)CSPLIT * NQ);
    int*      out   = (int*)d_out;

    ynorm_kernel<<<NTOK / TPB, TPB, 0, stream>>>(W, ynorm);
    wsplit_kernel<<<(NTOK * 8) / TPB, TPB, 0, stream>>>(W, Wh, Wl);
    dim3 grid(NQ / BQ, CSPLIT);
    vq_mfma_kernel<<<grid, TPB, 0, stream>>>(X, Wh, Wl, ynorm, pval, pidx);
    combine_kernel<<<NQ / TPB, TPB, 0, stream>>>(pval, pidx, out);
}